// Round 1
// baseline (247.257 us; speedup 1.0000x reference)
//
#include <hip/hip_runtime.h>

#define WIDTH  1024
#define HEIGHT 1024
#define R      4            // rows computed per block; HEIGHT % R == 0 so blocks never straddle images

typedef float vfloat4 __attribute__((ext_vector_type(4)));

__global__ __launch_bounds__(256) void fdtd_kernel(
    const float* __restrict__ u1,
    const float* __restrict__ u0,
    const float* __restrict__ j2,
    const float* __restrict__ j0,
    float* __restrict__ out,
    int chunk)                              // gridDim.x / 8 (0 => no swizzle)
{
    // XCD-aware chunked swizzle: consecutive row-blocks land on the same XCD's L2,
    // so the 2 u1 rows shared between adjacent blocks become L2 hits.
    const int bid = blockIdx.x;
    const int swz = chunk ? ((bid & 7) * chunk + (bid >> 3)) : bid;

    const int y0 = swz * R;                 // first computed global row
    const int iy = y0 & (HEIGHT - 1);       // row within image (block fully inside one image)
    const int x0 = threadIdx.x << 2;        // 4 floats per thread, full 1024-wide row per block
    const long base = (long)y0 * WIDTH + x0;
    const vfloat4 zero = {0.f, 0.f, 0.f, 0.f};

    // ---- u1: R+2 rows in registers (interior up/dn come for free) ----
    vfloat4 c[R + 2];
    c[0] = (iy > 0) ? *(const vfloat4*)(u1 + base - WIDTH) : zero;
#pragma unroll
    for (int r = 0; r < R; ++r)
        c[r + 1] = *(const vfloat4*)(u1 + base + (long)r * WIDTH);
    c[R + 1] = (iy + R < HEIGHT) ? *(const vfloat4*)(u1 + base + (long)R * WIDTH) : zero;

    // ---- x-edge neighbors (L1 hits: same rows just fetched) ----
    float lf[R], rt[R];
#pragma unroll
    for (int r = 0; r < R; ++r) {
        lf[r] = (x0 > 0)         ? u1[base + (long)r * WIDTH - 1] : 0.f;
        rt[r] = (x0 + 4 < WIDTH) ? u1[base + (long)r * WIDTH + 4] : 0.f;
    }

    // ---- streamed operands: nontemporal, keep L2/L3 for u1 ----
    vfloat4 a0[R], v2[R], v0[R];
#pragma unroll
    for (int r = 0; r < R; ++r) {
        const long b = base + (long)r * WIDTH;
        a0[r] = __builtin_nontemporal_load((const vfloat4*)(u0 + b));
        v2[r] = __builtin_nontemporal_load((const vfloat4*)(j2 + b));
        v0[r] = __builtin_nontemporal_load((const vfloat4*)(j0 + b));
    }

    // ---- compute + store ----
#pragma unroll
    for (int r = 0; r < R; ++r) {
        const vfloat4 up = c[r], ce = c[r + 1], dn = c[r + 2];
        vfloat4 o;
        o.x = 2.0f * ce.x - a0[r].x + 0.25f * (up.x + dn.x + lf[r] + ce.y - 4.0f * ce.x)
            - 0.0025f * (v2[r].x - v0[r].x);
        o.y = 2.0f * ce.y - a0[r].y + 0.25f * (up.y + dn.y + ce.x + ce.z - 4.0f * ce.y)
            - 0.0025f * (v2[r].y - v0[r].y);
        o.z = 2.0f * ce.z - a0[r].z + 0.25f * (up.z + dn.z + ce.y + ce.w - 4.0f * ce.z)
            - 0.0025f * (v2[r].z - v0[r].z);
        o.w = 2.0f * ce.w - a0[r].w + 0.25f * (up.w + dn.w + ce.z + rt[r] - 4.0f * ce.w)
            - 0.0025f * (v2[r].w - v0[r].w);
        __builtin_nontemporal_store(o, (vfloat4*)(out + base + (long)r * WIDTH));
    }
}

extern "C" void kernel_launch(void* const* d_in, const int* in_sizes, int n_in,
                              void* d_out, int out_size, void* d_ws, size_t ws_size,
                              hipStream_t stream) {
    const float* u1 = (const float*)d_in[0];
    const float* u0 = (const float*)d_in[1];
    const float* j2 = (const float*)d_in[2];
    const float* j0 = (const float*)d_in[3];
    float* out = (float*)d_out;

    const int nrows   = out_size / WIDTH;   // B*H = 16384 (out_size is element count)
    const int nblocks = nrows / R;          // 4096
    const int chunk   = (nblocks % 8 == 0) ? (nblocks >> 3) : 0;

    dim3 block(WIDTH / 4);                  // 256 threads: one full row per block-row
    dim3 grid(nblocks);
    fdtd_kernel<<<grid, block, 0, stream>>>(u1, u0, j2, j0, out, chunk);
}